// Round 6
// baseline (71.452 us; speedup 1.0000x reference)
//
#include <hip/hip_runtime.h>

#define D 300
#define NS 256
#define NA 256
#define W 8
#define NROWS 2048   // 256*8
#define KP 304       // D padded to multiple of 16
#define BK 16
#define NSTAGE (KP / BK)   // 19
#define FR 12              // B fragment slot stride (floats): 8 data + 4 pad
#define KROW 196           // B k-plane stride (floats): 16*FR + 4
#define ATS 2048           // AT row stride (floats)

// ------- gather + reciprocal norms + none flags + sen_wd_emb (merged) -------
__global__ __launch_bounds__(64) void k_gather(const float* __restrict__ emb,
                                               const int* __restrict__ sen_cats,
                                               const int* __restrict__ ann_cats,
                                               const int* __restrict__ none_idx,
                                               float* __restrict__ Arow,
                                               float* __restrict__ Brow,
                                               float* __restrict__ rsn,
                                               float* __restrict__ ran,
                                               int* __restrict__ sflag,
                                               float* __restrict__ out2) {
    int b = blockIdx.x, tid = threadIdx.x;
    if (b < NS) {
        bool has2 = (tid + 64) < 75;            // 75 float4 per row
        float4 sum0 = make_float4(0.f, 0.f, 0.f, 0.f);
        float4 sum1 = make_float4(0.f, 0.f, 0.f, 0.f);
        int nidx = none_idx[0];
        for (int w = 0; w < W; ++w) {
            int r = b * W + w;
            int cat = sen_cats[r];
            const float4* src = reinterpret_cast<const float4*>(emb + (size_t)cat * D);
            float4* dst = reinterpret_cast<float4*>(Arow + (size_t)r * KP);
            float4 v0 = src[tid];
            dst[tid] = v0;
            double acc = (double)v0.x * v0.x + (double)v0.y * v0.y +
                         (double)v0.z * v0.z + (double)v0.w * v0.w;
            sum0.x += v0.x; sum0.y += v0.y; sum0.z += v0.z; sum0.w += v0.w;
            if (has2) {
                float4 v1 = src[tid + 64];
                dst[tid + 64] = v1;
                acc += (double)v1.x * v1.x + (double)v1.y * v1.y +
                       (double)v1.z * v1.z + (double)v1.w * v1.w;
                sum1.x += v1.x; sum1.y += v1.y; sum1.z += v1.z; sum1.w += v1.w;
            }
            if (tid == 0) dst[75] = make_float4(0.f, 0.f, 0.f, 0.f);  // K-pad
            for (int off = 32; off > 0; off >>= 1) acc += __shfl_down(acc, off, 64);
            if (tid == 0) {
                rsn[r] = (float)(1.0 / sqrt(acc));
                sflag[r] = (cat == nidx) ? 1 : 0;
            }
        }
        float4* o = reinterpret_cast<float4*>(out2 + (size_t)b * D);
        o[tid] = sum0;
        if (has2) o[tid + 64] = sum1;
    } else {
        int r = b - NS;
        int cat = ann_cats[r];
        const float4* src = reinterpret_cast<const float4*>(emb + (size_t)cat * D);
        float4* dst = reinterpret_cast<float4*>(Brow + (size_t)r * KP);
        double acc = 0.0;
        for (int i = tid; i < 75; i += 64) {
            float4 v = src[i];
            dst[i] = v;
            acc += (double)v.x * v.x + (double)v.y * v.y +
                   (double)v.z * v.z + (double)v.w * v.w;
        }
        if (tid == 0) dst[75] = make_float4(0.f, 0.f, 0.f, 0.f);
        for (int off = 32; off > 0; off >>= 1) acc += __shfl_down(acc, off, 64);
        if (tid == 0) ran[r] = (float)(1.0 / sqrt(acc));
    }
}

// ---------------- transpose Arow[2048][KP] -> AT[KP][2048] ----------------
__global__ __launch_bounds__(256) void k_transpose(const float* __restrict__ Arow,
                                                   float* __restrict__ AT) {
    __shared__ float t[64][65];
    int si = blockIdx.x;          // s-rows si*64..+63
    int kt = blockIdx.y;          // k kt*64..+63 (guarded vs KP)
    int tid = threadIdx.x;
    int f = tid & 15;
    int rr = tid >> 4;
    int kbase = kt * 64;
#pragma unroll
    for (int p = 0; p < 4; ++p) {
        int r = p * 16 + rr;
        int k = kbase + f * 4;
        if (k < KP) {
            float4 v = *reinterpret_cast<const float4*>(
                Arow + (size_t)(si * 64 + r) * KP + k);
            t[r][f * 4 + 0] = v.x; t[r][f * 4 + 1] = v.y;
            t[r][f * 4 + 2] = v.z; t[r][f * 4 + 3] = v.w;
        }
    }
    __syncthreads();
#pragma unroll
    for (int p = 0; p < 4; ++p) {
        int kl = p * 16 + rr;
        int k = kbase + kl;
        if (k < KP) {
            float4 v = make_float4(t[f * 4 + 0][kl], t[f * 4 + 1][kl],
                                   t[f * 4 + 2][kl], t[f * 4 + 3][kl]);
            *reinterpret_cast<float4*>(AT + (size_t)k * ATS + si * 64 + f * 4) = v;
        }
    }
}

// --- main: A from transposed global (TA pipe), B from LDS (dbuf), in-reg fold ---
__global__ __launch_bounds__(256, 1) void k_main(const float* __restrict__ AT,
                                                 const float* __restrict__ Brow,
                                                 const float* __restrict__ rsn,
                                                 const float* __restrict__ ran,
                                                 const int* __restrict__ sflag,
                                                 float* __restrict__ out) {
    __shared__ float Bs[2][BK][KROW];

    int tid = threadIdx.x;
    int wv = tid >> 6, lane = tid & 63;
    int qy = wv >> 1, qx = wv & 1;
    int ty8 = lane >> 3, tx8 = lane & 7;
    int by = blockIdx.y, bx = blockIdx.x;

    const float* Ap = AT + (by * 128 + qy * 64 + ty8 * 8);   // + gk*ATS
    int bOff = (qx * 8 + tx8) * FR;

    // B staging map
    int q = tid & 3, r0 = tid >> 2;
    int kb = q * 4;
    int frag0 = (r0 >> 3) * FR + (r0 & 7);
    int frag1 = frag0 + 8 * FR;
    const float* Bg = Brow + (size_t)(bx * 128 + r0) * KP + q * 4;

    // prologue: stage 0 of B into buffer 0
    float4 pb0 = *reinterpret_cast<const float4*>(Bg);
    float4 pb1 = *reinterpret_cast<const float4*>(Bg + 64 * KP);
    {
        float bv0[4] = {pb0.x, pb0.y, pb0.z, pb0.w};
        float bv1[4] = {pb1.x, pb1.y, pb1.z, pb1.w};
#pragma unroll
        for (int i = 0; i < 4; ++i) {
            Bs[0][kb + i][frag0] = bv0[i];
            Bs[0][kb + i][frag1] = bv1[i];
        }
    }

    // A ring: 4-deep prefetch (slots indexed by gk&3, static under unroll)
    float4 aq0[4], aq1[4];
#pragma unroll
    for (int i = 0; i < 4; ++i) {
        aq0[i] = *reinterpret_cast<const float4*>(Ap + (size_t)i * ATS);
        aq1[i] = *reinterpret_cast<const float4*>(Ap + (size_t)i * ATS + 4);
    }

    float acc[W][W] = {};

    for (int st = 0; st < NSTAGE; ++st) {
        int cur = st & 1;
        __syncthreads();   // stage st's B writes visible; prev reads done
        // next-stage B global loads (used only at stage end)
        if (st + 1 < NSTAGE) {
            const float* Bg2 = Bg + (st + 1) * BK;
            pb0 = *reinterpret_cast<const float4*>(Bg2);
            pb1 = *reinterpret_cast<const float4*>(Bg2 + 64 * KP);
        }
        const float* Bbase = &Bs[cur][0][0];
        float4 b0c = *reinterpret_cast<const float4*>(Bbase + bOff);
        float4 b1c = *reinterpret_cast<const float4*>(Bbase + bOff + 4);
#pragma unroll
        for (int kk = 0; kk < BK; ++kk) {
            int gk = st * BK + kk;
            float4 a0 = aq0[kk & 3], a1 = aq1[kk & 3];
            float4 b0n, b1n;
            if (kk + 1 < BK) {   // B 1-deep pipeline
                const float* Bn = Bbase + (kk + 1) * KROW;
                b0n = *reinterpret_cast<const float4*>(Bn + bOff);
                b1n = *reinterpret_cast<const float4*>(Bn + bOff + 4);
            }
            // refill A slot with gk+4 (AT padded with 4 extra rows)
            aq0[kk & 3] = *reinterpret_cast<const float4*>(Ap + (size_t)(gk + 4) * ATS);
            aq1[kk & 3] = *reinterpret_cast<const float4*>(Ap + (size_t)(gk + 4) * ATS + 4);

            float av[W] = {a0.x, a0.y, a0.z, a0.w, a1.x, a1.y, a1.z, a1.w};
            float bv[W] = {b0c.x, b0c.y, b0c.z, b0c.w, b1c.x, b1c.y, b1c.z, b1c.w};
#pragma unroll
            for (int w = 0; w < W; ++w)
#pragma unroll
                for (int v = 0; v < W; ++v)
                    acc[w][v] = __builtin_fmaf(av[w], bv[v], acc[w][v]);
            if (kk + 1 < BK) { b0c = b0n; b1c = b1n; }
        }
        // write next B stage into the other buffer
        if (st + 1 < NSTAGE) {
            int nxt = cur ^ 1;
            float bv0[4] = {pb0.x, pb0.y, pb0.z, pb0.w};
            float bv1[4] = {pb1.x, pb1.y, pb1.z, pb1.w};
#pragma unroll
            for (int i = 0; i < 4; ++i) {
                Bs[nxt][kb + i][frag0] = bv0[i];
                Bs[nxt][kb + i][frag1] = bv1[i];
            }
        }
    }

    // epilogue: cosine + order-dependent fold, all in registers (fp32)
    int s = by * 16 + qy * 8 + ty8;
    int a = bx * 16 + qx * 8 + tx8;
    float rs[W], ra[W];
    int fl[W];
#pragma unroll
    for (int w = 0; w < W; ++w) {
        rs[w] = rsn[s * W + w];
        fl[w] = sflag[s * W + w];
    }
#pragma unroll
    for (int v = 0; v < W; ++v) ra[v] = ran[a * W + v];

    float cur = 0.f;
#pragma unroll
    for (int w = 0; w < W; ++w) {
        float rw = rs[w];
        int f = fl[w];
#pragma unroll
        for (int v = 0; v < W; ++v) {
            float cv = f ? 0.f : acc[w][v] * (rw * ra[v]);
            cur = (cv >= cur || cv < 0.f) ? cv : cur;
        }
    }
    out[s * NA + a] = cur;
}

extern "C" void kernel_launch(void* const* d_in, const int* in_sizes, int n_in,
                              void* d_out, int out_size, void* d_ws, size_t ws_size,
                              hipStream_t stream) {
    const float* emb = (const float*)d_in[0];
    const int* sen = (const int*)d_in[1];
    const int* ann = (const int*)d_in[2];
    const int* none = (const int*)d_in[3];
    float* out = (float*)d_out;

    char* ws = (char*)d_ws;
    float* Arow = (float*)(ws + 0);                  // 2048*304*4 = 2,490,368
    float* Brow = (float*)(ws + 2490368);            // 2,490,368
    float* AT   = (float*)(ws + 4980736);            // (304+4)*2048*4 = 2,523,136
    float* rsn  = (float*)(ws + 7503872);            // 8,192
    float* ran  = (float*)(ws + 7512064);            // 8,192
    int* sflag  = (int*)(ws + 7520256);              // 8,192

    hipLaunchKernelGGL(k_gather, dim3(NS + NROWS), dim3(64), 0, stream,
                       emb, sen, ann, none, Arow, Brow, rsn, ran, sflag,
                       out + NS * NA);
    hipLaunchKernelGGL(k_transpose, dim3(32, 5), dim3(256), 0, stream,
                       Arow, AT);
    hipLaunchKernelGGL(k_main, dim3(16, 16), dim3(256), 0, stream,
                       AT, Brow, rsn, ran, sflag, out);
}

// Round 7
// 39.576 us; speedup vs baseline: 1.8054x; 1.8054x over previous
//
#include <hip/hip_runtime.h>
#include <hip/hip_fp16.h>

#define D 300
#define NS 256
#define NA 256
#define W 8
#define NROWS 2048    // 256*8
#define KP2 320       // K padded to 10 chunks of 32
#define NCHUNK 10

typedef _Float16 half8 __attribute__((ext_vector_type(8)));
typedef float f32x4 __attribute__((ext_vector_type(4)));

// ---- gather: fp16 hi/lo split + reciprocal norms + none flags + sen_wd_emb ----
__global__ __launch_bounds__(64) void k_gather(const float* __restrict__ emb,
                                               const int* __restrict__ sen_cats,
                                               const int* __restrict__ ann_cats,
                                               const int* __restrict__ none_idx,
                                               unsigned short* __restrict__ AHI,
                                               unsigned short* __restrict__ ALO,
                                               unsigned short* __restrict__ BHI,
                                               unsigned short* __restrict__ BLO,
                                               float* __restrict__ rsn,
                                               float* __restrict__ ran,
                                               int* __restrict__ sflag,
                                               float* __restrict__ out2) {
    int b = blockIdx.x, tid = threadIdx.x;

    auto split_store = [&](float4 v, unsigned short* hi, unsigned short* lo,
                           size_t base, int i4) {
        float xs[4] = {v.x, v.y, v.z, v.w};
        ushort4 h, l;
        unsigned short* hp = &h.x;
        unsigned short* lp = &l.x;
#pragma unroll
        for (int j = 0; j < 4; ++j) {
            __half hh = __float2half(xs[j]);
            float hf = __half2float(hh);
            __half ll = __float2half(xs[j] - hf);
            hp[j] = __half_as_ushort(hh);
            lp[j] = __half_as_ushort(ll);
        }
        *reinterpret_cast<ushort4*>(hi + base + i4 * 4) = h;
        *reinterpret_cast<ushort4*>(lo + base + i4 * 4) = l;
    };

    if (b < NS) {
        bool has2 = (tid + 64) < 75;            // 75 float4 per row
        float4 sum0 = make_float4(0.f, 0.f, 0.f, 0.f);
        float4 sum1 = make_float4(0.f, 0.f, 0.f, 0.f);
        int nidx = none_idx[0];
        for (int w = 0; w < W; ++w) {
            int r = b * W + w;
            int cat = sen_cats[r];
            const float4* src = reinterpret_cast<const float4*>(emb + (size_t)cat * D);
            size_t base = (size_t)r * KP2;
            float4 v0 = src[tid];
            split_store(v0, AHI, ALO, base, tid);
            double acc = (double)v0.x * v0.x + (double)v0.y * v0.y +
                         (double)v0.z * v0.z + (double)v0.w * v0.w;
            sum0.x += v0.x; sum0.y += v0.y; sum0.z += v0.z; sum0.w += v0.w;
            if (has2) {
                float4 v1 = src[tid + 64];
                split_store(v1, AHI, ALO, base, tid + 64);
                acc += (double)v1.x * v1.x + (double)v1.y * v1.y +
                       (double)v1.z * v1.z + (double)v1.w * v1.w;
                sum1.x += v1.x; sum1.y += v1.y; sum1.z += v1.z; sum1.w += v1.w;
            }
            if (tid >= 75 && tid < 80) {        // zero K-pad elems 300..319
                ushort4 z = {0, 0, 0, 0};
                *reinterpret_cast<ushort4*>(AHI + base + tid * 4) = z;
                *reinterpret_cast<ushort4*>(ALO + base + tid * 4) = z;
            }
            for (int off = 32; off > 0; off >>= 1) acc += __shfl_down(acc, off, 64);
            if (tid == 0) {
                rsn[r] = (float)(1.0 / sqrt(acc));   // norms ~17, eps unreachable
                sflag[r] = (cat == nidx) ? 1 : 0;
            }
        }
        float4* o = reinterpret_cast<float4*>(out2 + (size_t)b * D);
        o[tid] = sum0;
        if (has2) o[tid + 64] = sum1;
    } else {
        int r = b - NS;
        int cat = ann_cats[r];
        const float4* src = reinterpret_cast<const float4*>(emb + (size_t)cat * D);
        size_t base = (size_t)r * KP2;
        double acc = 0.0;
        for (int i = tid; i < 75; i += 64) {
            float4 v = src[i];
            split_store(v, BHI, BLO, base, i);
            acc += (double)v.x * v.x + (double)v.y * v.y +
                   (double)v.z * v.z + (double)v.w * v.w;
        }
        if (tid >= 75 && tid < 80) {
            ushort4 z = {0, 0, 0, 0};
            *reinterpret_cast<ushort4*>(BHI + base + tid * 4) = z;
            *reinterpret_cast<ushort4*>(BLO + base + tid * 4) = z;
        }
        for (int off = 32; off > 0; off >>= 1) acc += __shfl_down(acc, off, 64);
        if (tid == 0) ran[r] = (float)(1.0 / sqrt(acc));
    }
}

// ---- main: 3-pass fp16-split MFMA GEMM, operands direct from global ----
__global__ __launch_bounds__(256, 1) void k_main(const unsigned short* __restrict__ AHIu,
                                                 const unsigned short* __restrict__ ALOu,
                                                 const unsigned short* __restrict__ BHIu,
                                                 const unsigned short* __restrict__ BLOu,
                                                 const float* __restrict__ rsn,
                                                 const float* __restrict__ ran,
                                                 const int* __restrict__ sflag,
                                                 float* __restrict__ out) {
    const _Float16* AHI = reinterpret_cast<const _Float16*>(AHIu);
    const _Float16* ALO = reinterpret_cast<const _Float16*>(ALOu);
    const _Float16* BHI = reinterpret_cast<const _Float16*>(BHIu);
    const _Float16* BLO = reinterpret_cast<const _Float16*>(BLOu);

    __shared__ float cosld[128][128];   // 64 KB exactly

    int tid = threadIdx.x;
    int wv = tid >> 6, lane = tid & 63;
    int wy = wv >> 1, wx = wv & 1;      // wave's 64x64 quadrant of the 128x128 tile
    int lr = lane & 15;                 // row (A) / col (B) within a 16x16 tile
    int lk = lane >> 4;                 // k-octet group (0..3)
    int by = blockIdx.y, bx = blockIdx.x;

    // per-m/n fragment base offsets (elements)
    size_t aBase[4], bBase[4];
#pragma unroll
    for (int m = 0; m < 4; ++m)
        aBase[m] = (size_t)(by * 128 + wy * 64 + m * 16 + lr) * KP2 + lk * 8;
#pragma unroll
    for (int n = 0; n < 4; ++n)
        bBase[n] = (size_t)(bx * 128 + wx * 64 + n * 16 + lr) * KP2 + lk * 8;

    f32x4 acc[4][4] = {};

    half8 cAh[4], cAl[4], cBh[4], cBl[4];   // current chunk
    half8 nAh[4], nAl[4], nBh[4], nBl[4];   // next chunk

    auto LOAD = [&](int c, half8* Ah, half8* Al, half8* Bh, half8* Bl) {
        int co = c * 32;
#pragma unroll
        for (int m = 0; m < 4; ++m) {
            Ah[m] = *reinterpret_cast<const half8*>(AHI + aBase[m] + co);
            Al[m] = *reinterpret_cast<const half8*>(ALO + aBase[m] + co);
        }
#pragma unroll
        for (int n = 0; n < 4; ++n) {
            Bh[n] = *reinterpret_cast<const half8*>(BHI + bBase[n] + co);
            Bl[n] = *reinterpret_cast<const half8*>(BLO + bBase[n] + co);
        }
    };
    auto COMPUTE = [&](half8* Ah, half8* Al, half8* Bh, half8* Bl) {
#pragma unroll
        for (int m = 0; m < 4; ++m)
#pragma unroll
            for (int n = 0; n < 4; ++n) {
                acc[m][n] = __builtin_amdgcn_mfma_f32_16x16x32_f16(Ah[m], Bh[n], acc[m][n], 0, 0, 0);
                acc[m][n] = __builtin_amdgcn_mfma_f32_16x16x32_f16(Ah[m], Bl[n], acc[m][n], 0, 0, 0);
                acc[m][n] = __builtin_amdgcn_mfma_f32_16x16x32_f16(Al[m], Bh[n], acc[m][n], 0, 0, 0);
            }
    };

    LOAD(0, cAh, cAl, cBh, cBl);
#pragma unroll
    for (int c = 0; c < NCHUNK; c += 2) {
        if (c + 1 < NCHUNK) LOAD(c + 1, nAh, nAl, nBh, nBl);
        COMPUTE(cAh, cAl, cBh, cBl);
        if (c + 2 < NCHUNK) LOAD(c + 2, cAh, cAl, cBh, cBl);
        if (c + 1 < NCHUNK) COMPUTE(nAh, nAl, nBh, nBl);
    }

    // epilogue: cosine scale (C/D layout: col=lane&15, row=(lane>>4)*4+reg) -> LDS
#pragma unroll
    for (int m = 0; m < 4; ++m) {
        int rbase = wy * 64 + m * 16 + lk * 4;
#pragma unroll
        for (int r = 0; r < 4; ++r) {
            int grow = by * 128 + rbase + r;
            float rsv = rsn[grow];
            float fm = sflag[grow] ? 0.f : 1.f;
            float rf = rsv * fm;
#pragma unroll
            for (int n = 0; n < 4; ++n) {
                int lc = wx * 64 + n * 16 + lr;
                float rav = ran[bx * 128 + lc];
                cosld[rbase + r][lc] = acc[m][n][r] * rf * rav;
            }
        }
    }
    __syncthreads();

    // order-dependent fold: one (s,a) pair per thread, w-major order
    int pi = tid >> 4, pj = tid & 15;
    float cur = 0.f;
#pragma unroll
    for (int w = 0; w < W; ++w) {
        const float* rowp = &cosld[pi * 8 + w][pj * 8];
#pragma unroll
        for (int v = 0; v < W; ++v) {
            float sv = rowp[v];
            cur = (sv >= cur || sv < 0.f) ? sv : cur;
        }
    }
    out[(by * 16 + pi) * NA + (bx * 16 + pj)] = cur;
}

extern "C" void kernel_launch(void* const* d_in, const int* in_sizes, int n_in,
                              void* d_out, int out_size, void* d_ws, size_t ws_size,
                              hipStream_t stream) {
    const float* emb = (const float*)d_in[0];
    const int* sen = (const int*)d_in[1];
    const int* ann = (const int*)d_in[2];
    const int* none = (const int*)d_in[3];
    float* out = (float*)d_out;

    char* ws = (char*)d_ws;
    unsigned short* AHI = (unsigned short*)(ws + 0);         // 2048*320*2 = 1,310,720
    unsigned short* ALO = (unsigned short*)(ws + 1310720);
    unsigned short* BHI = (unsigned short*)(ws + 2621440);
    unsigned short* BLO = (unsigned short*)(ws + 3932160);
    float* rsn = (float*)(ws + 5242880);                     // 8,192
    float* ran = (float*)(ws + 5251072);                     // 8,192
    int* sflag = (int*)(ws + 5259264);                       // 8,192

    hipLaunchKernelGGL(k_gather, dim3(NS + NROWS), dim3(64), 0, stream,
                       emb, sen, ann, none, AHI, ALO, BHI, BLO,
                       rsn, ran, sflag, out + NS * NA);
    hipLaunchKernelGGL(k_main, dim3(16, 16), dim3(256), 0, stream,
                       AHI, ALO, BHI, BLO, rsn, ran, sflag, out);
}

// Round 8
// 35.441 us; speedup vs baseline: 2.0161x; 1.1167x over previous
//
#include <hip/hip_runtime.h>
#include <hip/hip_fp16.h>

#define D 300
#define NS 256
#define NA 256
#define W 8
#define NROWS 2048    // 256*8
#define NCHUNK 10     // K padded to 10 chunks of 32 (320)

typedef _Float16 half8 __attribute__((ext_vector_type(8)));
typedef float f32x4 __attribute__((ext_vector_type(4)));

// Swizzled operand layout (halves): [rt(128)][c(10)][lane(64)][e(8)]
// lane = lk*16 + lr, where row = rt*16+lr, k = c*32 + lk*8 + e.
__device__ __forceinline__ int swaddr(int rt, int lr, int k4) {
    int c = k4 >> 5, lk = (k4 & 31) >> 3, e = k4 & 7;   // e in {0,4}
    return ((rt * NCHUNK + c) * 64 + lk * 16 + lr) * 8 + e;
}

__device__ __forceinline__ void split4(float4 v, ushort4& h, ushort4& l) {
    float xs[4] = {v.x, v.y, v.z, v.w};
    unsigned short* hp = &h.x;
    unsigned short* lp = &l.x;
#pragma unroll
    for (int j = 0; j < 4; ++j) {
        __half hh = __float2half(xs[j]);
        float hf = __half2float(hh);
        __half ll = __float2half(xs[j] - hf);
        hp[j] = __half_as_ushort(hh);
        lp[j] = __half_as_ushort(ll);
    }
}

// ---- gather: one wave per task (256 sen categories + 2048 ann rows) ----
__global__ __launch_bounds__(256) void k_gather(const float* __restrict__ emb,
                                                const int* __restrict__ sen_cats,
                                                const int* __restrict__ ann_cats,
                                                const int* __restrict__ none_idx,
                                                unsigned short* __restrict__ AHI,
                                                unsigned short* __restrict__ ALO,
                                                unsigned short* __restrict__ BHI,
                                                unsigned short* __restrict__ BLO,
                                                float* __restrict__ rsn,
                                                float* __restrict__ ran,
                                                int* __restrict__ sflag,
                                                float* __restrict__ out2) {
    int tid = threadIdx.x;
    int wv = tid >> 6, lane = tid & 63;
    int task = blockIdx.x * 4 + wv;

    if (task < NS) {
        int b = task;
        bool has2 = (lane + 64) < 75;            // lane < 11
        float4 sum0 = make_float4(0.f, 0.f, 0.f, 0.f);
        float4 sum1 = make_float4(0.f, 0.f, 0.f, 0.f);
        int nidx = none_idx[0];
        for (int w = 0; w < W; ++w) {
            int r = b * W + w;
            int cat = sen_cats[r];
            const float4* src = reinterpret_cast<const float4*>(emb + (size_t)cat * D);
            int rt = r >> 4, lr = r & 15;
            float4 v0 = src[lane];
            ushort4 h0, l0;
            split4(v0, h0, l0);
            int a0 = swaddr(rt, lr, lane * 4);
            *reinterpret_cast<ushort4*>(AHI + a0) = h0;
            *reinterpret_cast<ushort4*>(ALO + a0) = l0;
            double acc = (double)v0.x * v0.x + (double)v0.y * v0.y +
                         (double)v0.z * v0.z + (double)v0.w * v0.w;
            sum0.x += v0.x; sum0.y += v0.y; sum0.z += v0.z; sum0.w += v0.w;
            if (has2) {
                float4 v1 = src[lane + 64];
                ushort4 h1, l1;
                split4(v1, h1, l1);
                int a1 = swaddr(rt, lr, (lane + 64) * 4);
                *reinterpret_cast<ushort4*>(AHI + a1) = h1;
                *reinterpret_cast<ushort4*>(ALO + a1) = l1;
                acc += (double)v1.x * v1.x + (double)v1.y * v1.y +
                       (double)v1.z * v1.z + (double)v1.w * v1.w;
                sum1.x += v1.x; sum1.y += v1.y; sum1.z += v1.z; sum1.w += v1.w;
            } else if (lane < 16) {
                // zero K-pad: k = 300,304,308,312,316 (lanes 11..15)
                ushort4 z = {0, 0, 0, 0};
                int a1 = swaddr(rt, lr, (lane + 64) * 4);
                *reinterpret_cast<ushort4*>(AHI + a1) = z;
                *reinterpret_cast<ushort4*>(ALO + a1) = z;
            }
            for (int off = 32; off > 0; off >>= 1) acc += __shfl_down(acc, off, 64);
            if (lane == 0) {
                rsn[r] = (float)(1.0 / sqrt(acc));   // norms ~17, eps unreachable
                sflag[r] = (cat == nidx) ? 1 : 0;
            }
        }
        float4* o = reinterpret_cast<float4*>(out2 + (size_t)b * D);
        o[lane] = sum0;
        if (has2) o[lane + 64] = sum1;
    } else {
        int r = task - NS;   // ann row
        int cat = ann_cats[r];
        const float4* src = reinterpret_cast<const float4*>(emb + (size_t)cat * D);
        int rt = r >> 4, lr = r & 15;
        float4 v0 = src[lane];
        ushort4 h0, l0;
        split4(v0, h0, l0);
        int a0 = swaddr(rt, lr, lane * 4);
        *reinterpret_cast<ushort4*>(BHI + a0) = h0;
        *reinterpret_cast<ushort4*>(BLO + a0) = l0;
        double acc = (double)v0.x * v0.x + (double)v0.y * v0.y +
                     (double)v0.z * v0.z + (double)v0.w * v0.w;
        if (lane < 11) {
            float4 v1 = src[lane + 64];
            ushort4 h1, l1;
            split4(v1, h1, l1);
            int a1 = swaddr(rt, lr, (lane + 64) * 4);
            *reinterpret_cast<ushort4*>(BHI + a1) = h1;
            *reinterpret_cast<ushort4*>(BLO + a1) = l1;
            acc += (double)v1.x * v1.x + (double)v1.y * v1.y +
                   (double)v1.z * v1.z + (double)v1.w * v1.w;
        } else if (lane < 16) {
            ushort4 z = {0, 0, 0, 0};
            int a1 = swaddr(rt, lr, (lane + 64) * 4);
            *reinterpret_cast<ushort4*>(BHI + a1) = z;
            *reinterpret_cast<ushort4*>(BLO + a1) = z;
        }
        for (int off = 32; off > 0; off >>= 1) acc += __shfl_down(acc, off, 64);
        if (lane == 0) ran[r] = (float)(1.0 / sqrt(acc));
    }
}

// ---- main: 3-pass fp16-split MFMA GEMM, swizzled contiguous operand loads ----
__global__ __launch_bounds__(256, 1) void k_main(const unsigned short* __restrict__ AHIu,
                                                 const unsigned short* __restrict__ ALOu,
                                                 const unsigned short* __restrict__ BHIu,
                                                 const unsigned short* __restrict__ BLOu,
                                                 const float* __restrict__ rsn,
                                                 const float* __restrict__ ran,
                                                 const int* __restrict__ sflag,
                                                 float* __restrict__ out) {
    const _Float16* AHI = reinterpret_cast<const _Float16*>(AHIu);
    const _Float16* ALO = reinterpret_cast<const _Float16*>(ALOu);
    const _Float16* BHI = reinterpret_cast<const _Float16*>(BHIu);
    const _Float16* BLO = reinterpret_cast<const _Float16*>(BLOu);

    __shared__ float cosld[128][128];   // 64 KB exactly

    int tid = threadIdx.x;
    int wv = tid >> 6, lane = tid & 63;
    int wy = wv >> 1, wx = wv & 1;      // wave's 64x64 quadrant
    int lr = lane & 15;
    int lk = lane >> 4;
    int by = blockIdx.y, bx = blockIdx.x;

    // swizzled bases: element ((rt*10 + c)*64 + lane)*8 ; chunk stride 512
    int aBase[4], bBase[4];
#pragma unroll
    for (int m = 0; m < 4; ++m)
        aBase[m] = (((by * 8 + wy * 4 + m) * NCHUNK) * 64 + lane) * 8;
#pragma unroll
    for (int n = 0; n < 4; ++n)
        bBase[n] = (((bx * 8 + wx * 4 + n) * NCHUNK) * 64 + lane) * 8;

    f32x4 acc[4][4] = {};
    half8 Ah[4], Al[4], Bh[4], Bl[4];

#pragma unroll
    for (int c = 0; c < NCHUNK; ++c) {
        int co = c * 512;
#pragma unroll
        for (int m = 0; m < 4; ++m) {
            Ah[m] = *reinterpret_cast<const half8*>(AHI + aBase[m] + co);
            Al[m] = *reinterpret_cast<const half8*>(ALO + aBase[m] + co);
        }
#pragma unroll
        for (int n = 0; n < 4; ++n) {
            Bh[n] = *reinterpret_cast<const half8*>(BHI + bBase[n] + co);
            Bl[n] = *reinterpret_cast<const half8*>(BLO + bBase[n] + co);
        }
#pragma unroll
        for (int m = 0; m < 4; ++m)
#pragma unroll
            for (int n = 0; n < 4; ++n) {
                acc[m][n] = __builtin_amdgcn_mfma_f32_16x16x32_f16(Ah[m], Bh[n], acc[m][n], 0, 0, 0);
                acc[m][n] = __builtin_amdgcn_mfma_f32_16x16x32_f16(Ah[m], Bl[n], acc[m][n], 0, 0, 0);
                acc[m][n] = __builtin_amdgcn_mfma_f32_16x16x32_f16(Al[m], Bh[n], acc[m][n], 0, 0, 0);
            }
    }

    // epilogue: cosine scale (C/D layout: col=lane&15, row=(lane>>4)*4+reg) -> LDS
#pragma unroll
    for (int m = 0; m < 4; ++m) {
        int rbase = wy * 64 + m * 16 + lk * 4;
#pragma unroll
        for (int r = 0; r < 4; ++r) {
            int grow = by * 128 + rbase + r;
            float rsv = rsn[grow];
            float fm = sflag[grow] ? 0.f : 1.f;
            float rf = rsv * fm;
#pragma unroll
            for (int n = 0; n < 4; ++n) {
                int lc = wx * 64 + n * 16 + lr;
                float rav = ran[bx * 128 + lc];
                cosld[rbase + r][lc] = acc[m][n][r] * rf * rav;
            }
        }
    }
    __syncthreads();

    // order-dependent fold: one (s,a) pair per thread, w-major order
    int pi = tid >> 4, pj = tid & 15;
    float cur = 0.f;
#pragma unroll
    for (int w = 0; w < W; ++w) {
        const float* rowp = &cosld[pi * 8 + w][pj * 8];
#pragma unroll
        for (int v = 0; v < W; ++v) {
            float sv = rowp[v];
            cur = (sv >= cur || sv < 0.f) ? sv : cur;
        }
    }
    out[(by * 16 + pi) * NA + (bx * 16 + pj)] = cur;
}

extern "C" void kernel_launch(void* const* d_in, const int* in_sizes, int n_in,
                              void* d_out, int out_size, void* d_ws, size_t ws_size,
                              hipStream_t stream) {
    const float* emb = (const float*)d_in[0];
    const int* sen = (const int*)d_in[1];
    const int* ann = (const int*)d_in[2];
    const int* none = (const int*)d_in[3];
    float* out = (float*)d_out;

    char* ws = (char*)d_ws;
    unsigned short* AHI = (unsigned short*)(ws + 0);         // 2048*320*2 = 1,310,720
    unsigned short* ALO = (unsigned short*)(ws + 1310720);
    unsigned short* BHI = (unsigned short*)(ws + 2621440);
    unsigned short* BLO = (unsigned short*)(ws + 3932160);
    float* rsn = (float*)(ws + 5242880);                     // 8,192
    float* ran = (float*)(ws + 5251072);                     // 8,192
    int* sflag = (int*)(ws + 5259264);                       // 8,192

    hipLaunchKernelGGL(k_gather, dim3(576), dim3(256), 0, stream,
                       emb, sen, ann, none, AHI, ALO, BHI, BLO,
                       rsn, ran, sflag, out + NS * NA);
    hipLaunchKernelGGL(k_main, dim3(16, 16), dim3(256), 0, stream,
                       AHI, ALO, BHI, BLO, rsn, ran, sflag, out);
}